// Round 1
// baseline (16945.720 us; speedup 1.0000x reference)
//
#include <hip/hip_runtime.h>
#include <math.h>

#define TT 2048
#define II 64
#define HH 512
#define LL 5
#define RING 8
#define NBLK 160
#define STEPS (TT + LL - 1)   // 2052 pipeline steps

__device__ __forceinline__ float wave_sum(float v) {
#pragma unroll
  for (int m = 32; m > 0; m >>= 1) v += __shfl_xor(v, m, 64);
  return v;
}

__device__ __forceinline__ float wave_max(float v) {
#pragma unroll
  for (int m = 32; m > 0; m >>= 1) v = fmaxf(v, __shfl_xor(v, m, 64));
  return v;
}

__device__ __forceinline__ float sigmoidf_(float v) {
  return 1.0f / (1.0f + expf(-v));
}

// Sense-free monotonic grid barrier. arrive never resets; gen is monotone.
// Bounded spin + fetch_max escape so a residency failure degrades to wrong
// results instead of a hang.
__device__ __forceinline__ void grid_barrier(unsigned* arrive, unsigned* gen, unsigned idx) {
  __syncthreads();
  if (threadIdx.x == 0) {
    __threadfence();  // release: make prior stores device-visible
    unsigned target = (unsigned)NBLK * (idx + 1u);
    unsigned prev = __hip_atomic_fetch_add(arrive, 1u, __ATOMIC_RELAXED, __HIP_MEMORY_SCOPE_AGENT);
    if (prev + 1u == target) {
      __hip_atomic_store(gen, idx + 1u, __ATOMIC_RELAXED, __HIP_MEMORY_SCOPE_AGENT);
    } else {
      long spins = 0;
      while (__hip_atomic_load(gen, __ATOMIC_RELAXED, __HIP_MEMORY_SCOPE_AGENT) < idx + 1u) {
        if (++spins > 4000000L) {
          __hip_atomic_fetch_max(gen, idx + 1u, __ATOMIC_RELAXED, __HIP_MEMORY_SCOPE_AGENT);
          break;
        }
      }
    }
    __threadfence();  // acquire: invalidate stale cache before consuming
  }
  __syncthreads();
}

extern "C" __global__ void __launch_bounds__(1024) lstm_pipe(
    const float* __restrict__ x,
    const float* __restrict__ w_ih0, const float* __restrict__ w_hh0,
    const float* __restrict__ b_ih0, const float* __restrict__ b_hh0,
    const float* __restrict__ w_ih, const float* __restrict__ w_hh,
    const float* __restrict__ b_ih, const float* __restrict__ b_hh,
    const float* __restrict__ w_lin, const float* __restrict__ b_lin,
    float* __restrict__ out, float* __restrict__ ws) {
  // ws layout: [0B] arrive, [128B] gen, [256B..] float data
  unsigned* arrive = (unsigned*)ws;
  unsigned* gen = (unsigned*)(ws + 32);
  float* base = ws + 64;
  float* h_ring = base;                        // LL*RING*HH
  float* h4 = h_ring + LL * RING * HH;         // TT*HH
  float* h4T = h4 + (size_t)TT * HH;           // HH*TT
  float* scores = h4T + (size_t)HH * TT;       // TT
  float* pbuf = scores + TT;                   // TT
  float* red = pbuf + TT;                      // scale

  const int b = blockIdx.x;
  const int tid = threadIdx.x;
  const int wv = tid >> 6;
  const int lane = tid & 63;
  const int l = b >> 5;       // layer 0..4 (32 blocks each)
  const int q = b & 31;
  const int j = q * 16 + wv;  // h-output index 0..511 owned by this wave

  // ---- pin weights in registers ----
  float whh[4][8], wih[4][8], wih0[4], bias[4];
  const float* WHH = (l == 0) ? w_hh0 : (w_hh + (size_t)(l - 1) * 4 * HH * HH);
#pragma unroll
  for (int g = 0; g < 4; ++g) {
    const int row = g * HH + j;
    const float4* p = (const float4*)(WHH + (size_t)row * HH + lane * 8);
    float4 a = p[0], d = p[1];
    whh[g][0] = a.x; whh[g][1] = a.y; whh[g][2] = a.z; whh[g][3] = a.w;
    whh[g][4] = d.x; whh[g][5] = d.y; whh[g][6] = d.z; whh[g][7] = d.w;
  }
  if (l == 0) {
#pragma unroll
    for (int g = 0; g < 4; ++g) {
      const int row = g * HH + j;
      wih0[g] = w_ih0[(size_t)row * II + lane];
      bias[g] = b_ih0[row] + b_hh0[row];
#pragma unroll
      for (int m = 0; m < 8; ++m) wih[g][m] = 0.0f;
    }
  } else {
    const float* WIH = w_ih + (size_t)(l - 1) * 4 * HH * HH;
    const float* BIH = b_ih + (size_t)(l - 1) * 4 * HH;
    const float* BHH = b_hh + (size_t)(l - 1) * 4 * HH;
#pragma unroll
    for (int g = 0; g < 4; ++g) {
      const int row = g * HH + j;
      const float4* p = (const float4*)(WIH + (size_t)row * HH + lane * 8);
      float4 a = p[0], d = p[1];
      wih[g][0] = a.x; wih[g][1] = a.y; wih[g][2] = a.z; wih[g][3] = a.w;
      wih[g][4] = d.x; wih[g][5] = d.y; wih[g][6] = d.z; wih[g][7] = d.w;
      bias[g] = BIH[row] + BHH[row];
      wih0[g] = 0.0f;
    }
  }

  float c = 0.0f;

  // ---- pipelined recurrence: layer l handles t = s - l ----
  for (int s = 0; s < STEPS; ++s) {
    const int t = s - l;
    if (t >= 0 && t < TT) {
      float hp[8];
      if (t > 0) {
        const float4* p = (const float4*)(h_ring + ((size_t)l * RING + ((t - 1) & (RING - 1))) * HH + lane * 8);
        float4 a = p[0], d = p[1];
        hp[0] = a.x; hp[1] = a.y; hp[2] = a.z; hp[3] = a.w;
        hp[4] = d.x; hp[5] = d.y; hp[6] = d.z; hp[7] = d.w;
      } else {
#pragma unroll
        for (int m = 0; m < 8; ++m) hp[m] = 0.0f;
      }
      float ai = 0.0f, af = 0.0f, ag = 0.0f, ao = 0.0f;
#pragma unroll
      for (int m = 0; m < 8; ++m) {
        ai = fmaf(whh[0][m], hp[m], ai);
        af = fmaf(whh[1][m], hp[m], af);
        ag = fmaf(whh[2][m], hp[m], ag);
        ao = fmaf(whh[3][m], hp[m], ao);
      }
      if (l == 0) {
        float x0 = x[(size_t)t * II + lane];
        ai = fmaf(wih0[0], x0, ai);
        af = fmaf(wih0[1], x0, af);
        ag = fmaf(wih0[2], x0, ag);
        ao = fmaf(wih0[3], x0, ao);
      } else {
        const float4* p = (const float4*)(h_ring + ((size_t)(l - 1) * RING + (t & (RING - 1))) * HH + lane * 8);
        float4 a = p[0], d = p[1];
        float xin[8] = {a.x, a.y, a.z, a.w, d.x, d.y, d.z, d.w};
#pragma unroll
        for (int m = 0; m < 8; ++m) {
          ai = fmaf(wih[0][m], xin[m], ai);
          af = fmaf(wih[1][m], xin[m], af);
          ag = fmaf(wih[2][m], xin[m], ag);
          ao = fmaf(wih[3][m], xin[m], ao);
        }
      }
      ai = wave_sum(ai); af = wave_sum(af); ag = wave_sum(ag); ao = wave_sum(ao);
      float gi = sigmoidf_(ai + bias[0]);
      float gf = sigmoidf_(af + bias[1]);
      float gg = tanhf(ag + bias[2]);
      float go = sigmoidf_(ao + bias[3]);
      c = gf * c + gi * gg;
      float h = go * tanhf(c);
      if (lane == 0) {
        h_ring[((size_t)l * RING + (t & (RING - 1))) * HH + j] = h;
        if (l == 4) {
          h4[(size_t)t * HH + j] = h;
          h4T[(size_t)j * TT + t] = h;
        }
      }
    }
    grid_barrier(arrive, gen, (unsigned)s);
  }

  // ---- phase A: scores s_t = tanh(h4[t] . w_lin + b_lin) ----
  {
    const int gw = b * 16 + wv;
    if (gw < TT) {
      const int t = gw;
      const float4* hp4 = (const float4*)(h4 + (size_t)t * HH + lane * 8);
      const float4* wl4 = (const float4*)(w_lin + lane * 8);
      float4 a = hp4[0], d = hp4[1], wa = wl4[0], wd = wl4[1];
      float acc = 0.0f;
      acc = fmaf(a.x, wa.x, acc); acc = fmaf(a.y, wa.y, acc);
      acc = fmaf(a.z, wa.z, acc); acc = fmaf(a.w, wa.w, acc);
      acc = fmaf(d.x, wd.x, acc); acc = fmaf(d.y, wd.y, acc);
      acc = fmaf(d.z, wd.z, acc); acc = fmaf(d.w, wd.w, acc);
      acc = wave_sum(acc);
      float sc = tanhf(acc + b_lin[0]);
      if (lane == 0) scores[t] = sc;
    }
  }
  grid_barrier(arrive, gen, (unsigned)STEPS);

  // ---- phase B: softmax over time (block 0 only) ----
  __shared__ float sbuf[20];
  if (b == 0) {
    float s0 = scores[tid];
    float s1 = scores[tid + 1024];
    float m = fmaxf(s0, s1);
    m = wave_max(m);
    if (lane == 0) sbuf[wv] = m;
    __syncthreads();
    if (tid == 0) {
      float M = sbuf[0];
      for (int k = 1; k < 16; ++k) M = fmaxf(M, sbuf[k]);
      sbuf[16] = M;
    }
    __syncthreads();
    float M = sbuf[16];
    float p0 = expf(s0 - M), p1 = expf(s1 - M);
    pbuf[tid] = p0;
    pbuf[tid + 1024] = p1;
    float ssum = wave_sum(p0 + p1);
    __syncthreads();
    if (lane == 0) sbuf[wv] = ssum;
    __syncthreads();
    if (tid == 0) {
      float S = 0.0f;
      for (int k = 0; k < 16; ++k) S += sbuf[k];
      red[0] = 1.0f / ((float)TT * S);
    }
  }
  grid_barrier(arrive, gen, (unsigned)(STEPS + 1));

  // ---- phase C: res[j] = scale * sum_t p_t * h4T[j][t] ----
  {
    const int gw = b * 16 + wv;
    if (gw < HH) {
      const int jj = gw;
      const float scale = red[0];
      const float* hr = h4T + (size_t)jj * TT + lane * 32;
      const float* pr = pbuf + lane * 32;
      float acc = 0.0f;
#pragma unroll
      for (int m = 0; m < 32; ++m) acc = fmaf(hr[m], pr[m], acc);
      acc = wave_sum(acc);
      if (lane == 0) out[jj] = scale * acc;
    }
  }
}

extern "C" void kernel_launch(void* const* d_in, const int* in_sizes, int n_in,
                              void* d_out, int out_size, void* d_ws, size_t ws_size,
                              hipStream_t stream) {
  // zero the barrier counters (arrive/gen) — idempotent per launch
  hipMemsetAsync(d_ws, 0, 256, stream);
  lstm_pipe<<<dim3(NBLK), dim3(1024), 0, stream>>>(
      (const float*)d_in[0],
      (const float*)d_in[1], (const float*)d_in[2],
      (const float*)d_in[3], (const float*)d_in[4],
      (const float*)d_in[5], (const float*)d_in[6],
      (const float*)d_in[7], (const float*)d_in[8],
      (const float*)d_in[9], (const float*)d_in[10],
      (float*)d_out, (float*)d_ws);
}